// Round 1
// baseline (465.536 us; speedup 1.0000x reference)
//
#include <hip/hip_runtime.h>

// Problem constants (match reference setup_inputs)
#define BATCH 32768
#define LMAX  24
#define MOUT  10
#define DIM   300
#define VOCAB 36
#define D4    (DIM / 4)                 // 75 float4 per row
#define N4    (BATCH * MOUT * D4)      // 24,576,000 float4 output elements

__global__ __launch_bounds__(256) void word_emb_kernel(
    const float* __restrict__ emb,     // [VOCAB, DIM]
    const float* __restrict__ pad,     // [1, DIM]
    const int*   __restrict__ tokens,  // [BATCH, LMAX]
    const int*   __restrict__ lengths, // [BATCH]
    float4*      __restrict__ out)     // [BATCH, MOUT, DIM] as float4
{
    // Stage emb table + pad row into LDS (43.2 KB + 1.2 KB)
    __shared__ float lds_emb[VOCAB * DIM];
    __shared__ float lds_pad[DIM];
    {
        const float4* emb4 = (const float4*)emb;
        float4* lemb4 = (float4*)lds_emb;
        for (int i = threadIdx.x; i < VOCAB * D4; i += blockDim.x)
            lemb4[i] = emb4[i];
        const float4* pad4 = (const float4*)pad;
        float4* lpad4 = (float4*)lds_pad;
        for (int i = threadIdx.x; i < D4; i += blockDim.x)
            lpad4[i] = pad4[i];
    }
    __syncthreads();

    const int stride = gridDim.x * blockDim.x;
    for (int e = blockIdx.x * blockDim.x + threadIdx.x; e < N4; e += stride) {
        const int row = e / D4;             // word-row index = b*MOUT + i
        const int j   = e - row * D4;       // float4 index within the D row
        const int b   = row / MOUT;
        const int i   = row - b * MOUT;
        const int L   = lengths[b];

        float4 val;
        if (L < MOUT) {
            if (i < L) {
                const int tok = tokens[b * LMAX + i];
                val = *(const float4*)&lds_emb[tok * DIM + 4 * j];
            } else {
                val = *(const float4*)&lds_pad[4 * j];
            }
        } else {
            // bilinear along char axis, align_corners=True (width is identity)
            const float pos = (float)(i * (L - 1)) / (float)(MOUT - 1);
            const int   lo  = (int)floorf(pos);
            const int   hi  = min(lo + 1, L - 1);
            const float w   = pos - (float)lo;
            const int tlo = tokens[b * LMAX + lo];
            const int thi = tokens[b * LMAX + hi];
            const float4 glo = *(const float4*)&lds_emb[tlo * DIM + 4 * j];
            const float4 ghi = *(const float4*)&lds_emb[thi * DIM + 4 * j];
            const float wl = 1.0f - w;
            val.x = glo.x * wl + ghi.x * w;
            val.y = glo.y * wl + ghi.y * w;
            val.z = glo.z * wl + ghi.z * w;
            val.w = glo.w * wl + ghi.w * w;
        }
        out[e] = val;
    }
}

extern "C" void kernel_launch(void* const* d_in, const int* in_sizes, int n_in,
                              void* d_out, int out_size, void* d_ws, size_t ws_size,
                              hipStream_t stream) {
    const float* emb     = (const float*)d_in[0];
    const float* pad     = (const float*)d_in[1];
    const int*   tokens  = (const int*)d_in[2];
    const int*   lengths = (const int*)d_in[3];
    float4* out = (float4*)d_out;

    // LDS 44.4 KB -> 3 blocks/CU; 256 CUs * 3 = 768 resident blocks.
    const int blocks = 768;
    word_emb_kernel<<<blocks, 256, 0, stream>>>(emb, pad, tokens, lengths, out);
}

// Round 2
// 402.859 us; speedup vs baseline: 1.1556x; 1.1556x over previous
//
#include <hip/hip_runtime.h>

// Problem constants (match reference setup_inputs)
#define BATCH 32768
#define LMAX  24
#define MOUT  10
#define DIM   300
#define VOCAB 36
#define D4    (DIM / 4)                  // 75 float4 per row
#define NROW  (BATCH * MOUT)             // 327,680 output rows
#define N4    (NROW * D4)                // 24,576,000 float4 outputs
#define PAD_OFF (VOCAB * DIM)            // float offset of pad row inside LDS
#define LDSF  (VOCAB * DIM + DIM)        // 11,100 floats = 44.4 KB

// ---------------------------------------------------------------------------
// Pass 1: per-output-row descriptor {lo_off, hi_off, w}. Pad & copy branches
// unify as lo==hi, w=0, making the main kernel branch-free.
// ---------------------------------------------------------------------------
__global__ __launch_bounds__(256) void desc_kernel(
    const int* __restrict__ lengths,  // [BATCH]
    const int* __restrict__ tokens,   // [BATCH, LMAX]
    int4*      __restrict__ desc)     // [NROW]
{
    const int r = blockIdx.x * blockDim.x + threadIdx.x;
    if (r >= NROW) return;
    const int b = r / MOUT;
    const int i = r - b * MOUT;
    const int L = lengths[b];

    int lo_off, hi_off;
    float w;
    if (L < MOUT) {
        if (i < L) {
            lo_off = hi_off = tokens[b * LMAX + i] * DIM;
        } else {
            lo_off = hi_off = PAD_OFF;
        }
        w = 0.0f;
    } else {
        // exact reference arithmetic: pos = i*(L-1)/9 (all values integer-exact)
        const float pos = ((float)i * (float)(L - 1)) / (float)(MOUT - 1);
        const int   lo  = (int)floorf(pos);
        const int   hi  = min(lo + 1, L - 1);
        w = pos - (float)lo;
        lo_off = tokens[b * LMAX + lo] * DIM;
        hi_off = tokens[b * LMAX + hi] * DIM;
    }
    desc[r] = make_int4(lo_off, hi_off, __float_as_int(w), 0);
}

// ---------------------------------------------------------------------------
// Pass 2: branch-free gather+lerp. 750 blocks x 512 threads = 384,000 threads,
// N4 / 384,000 = 64 elements per thread exactly; unroll x4, no guards.
// LDS 44.4 KB @ 512 threads -> 3 blocks/CU = 24 waves/CU.
// ---------------------------------------------------------------------------
#define TPB   512
#define NBLK  750
#define NTHR  (TPB * NBLK)               // 384,000
#define ITERS (N4 / NTHR)                // 64

__global__ __launch_bounds__(TPB) void emb_kernel(
    const float* __restrict__ emb,    // [VOCAB, DIM]
    const float* __restrict__ pad,    // [1, DIM]
    const int4*  __restrict__ desc,   // [NROW]
    float4*      __restrict__ out)    // [N4]
{
    __shared__ float lds[LDSF];
    {
        const float4* e4 = (const float4*)emb;
        float4* l4 = (float4*)lds;
        for (int i = threadIdx.x; i < VOCAB * D4; i += TPB) l4[i] = e4[i];
        const float4* p4 = (const float4*)pad;
        for (int i = threadIdx.x; i < D4; i += TPB) l4[VOCAB * D4 + i] = p4[i];
    }
    __syncthreads();

    const int tid = blockIdx.x * TPB + threadIdx.x;
    const int stride = NTHR;

    int e = tid;
    for (int it = 0; it < ITERS / 4; ++it) {
        const int e0 = e, e1 = e + stride, e2 = e + 2 * stride, e3 = e + 3 * stride;

        // row/j decomposition (div by 75 -> magic mul)
        const int r0 = e0 / D4, r1 = e1 / D4, r2 = e2 / D4, r3 = e3 / D4;
        const int j0 = e0 - r0 * D4, j1 = e1 - r1 * D4, j2 = e2 - r2 * D4, j3 = e3 - r3 * D4;

        // 4 independent desc loads in flight
        const int4 d0 = desc[r0];
        const int4 d1 = desc[r1];
        const int4 d2 = desc[r2];
        const int4 d3 = desc[r3];

        const float4 a0 = *(const float4*)&lds[d0.x + 4 * j0];
        const float4 b0 = *(const float4*)&lds[d0.y + 4 * j0];
        const float4 a1 = *(const float4*)&lds[d1.x + 4 * j1];
        const float4 b1 = *(const float4*)&lds[d1.y + 4 * j1];
        const float4 a2 = *(const float4*)&lds[d2.x + 4 * j2];
        const float4 b2 = *(const float4*)&lds[d2.y + 4 * j2];
        const float4 a3 = *(const float4*)&lds[d3.x + 4 * j3];
        const float4 b3 = *(const float4*)&lds[d3.y + 4 * j3];

        const float w0 = __int_as_float(d0.z), u0 = 1.0f - w0;
        const float w1 = __int_as_float(d1.z), u1 = 1.0f - w1;
        const float w2 = __int_as_float(d2.z), u2 = 1.0f - w2;
        const float w3 = __int_as_float(d3.z), u3 = 1.0f - w3;

        float4 v0, v1, v2, v3;
        v0.x = a0.x * u0 + b0.x * w0; v0.y = a0.y * u0 + b0.y * w0;
        v0.z = a0.z * u0 + b0.z * w0; v0.w = a0.w * u0 + b0.w * w0;
        v1.x = a1.x * u1 + b1.x * w1; v1.y = a1.y * u1 + b1.y * w1;
        v1.z = a1.z * u1 + b1.z * w1; v1.w = a1.w * u1 + b1.w * w1;
        v2.x = a2.x * u2 + b2.x * w2; v2.y = a2.y * u2 + b2.y * w2;
        v2.z = a2.z * u2 + b2.z * w2; v2.w = a2.w * u2 + b2.w * w2;
        v3.x = a3.x * u3 + b3.x * w3; v3.y = a3.y * u3 + b3.y * w3;
        v3.z = a3.z * u3 + b3.z * w3; v3.w = a3.w * u3 + b3.w * w3;

        out[e0] = v0;
        out[e1] = v1;
        out[e2] = v2;
        out[e3] = v3;

        e += 4 * stride;
    }
}

// ---------------------------------------------------------------------------
// Fallback (ws too small): round-1 single-pass kernel (correct, slower).
// ---------------------------------------------------------------------------
__global__ __launch_bounds__(256) void emb_kernel_fallback(
    const float* __restrict__ emb, const float* __restrict__ pad,
    const int* __restrict__ tokens, const int* __restrict__ lengths,
    float4* __restrict__ out)
{
    __shared__ float lds[LDSF];
    {
        const float4* e4 = (const float4*)emb;
        float4* l4 = (float4*)lds;
        for (int i = threadIdx.x; i < VOCAB * D4; i += blockDim.x) l4[i] = e4[i];
        const float4* p4 = (const float4*)pad;
        for (int i = threadIdx.x; i < D4; i += blockDim.x) l4[VOCAB * D4 + i] = p4[i];
    }
    __syncthreads();
    const int stride = gridDim.x * blockDim.x;
    for (int e = blockIdx.x * blockDim.x + threadIdx.x; e < N4; e += stride) {
        const int row = e / D4;
        const int j = e - row * D4;
        const int b = row / MOUT;
        const int i = row - b * MOUT;
        const int L = lengths[b];
        float4 val;
        if (L < MOUT) {
            val = (i < L) ? *(const float4*)&lds[tokens[b * LMAX + i] * DIM + 4 * j]
                          : *(const float4*)&lds[PAD_OFF + 4 * j];
        } else {
            const float pos = ((float)i * (float)(L - 1)) / (float)(MOUT - 1);
            const int lo = (int)floorf(pos);
            const int hi = min(lo + 1, L - 1);
            const float w = pos - (float)lo;
            const float4 glo = *(const float4*)&lds[tokens[b * LMAX + lo] * DIM + 4 * j];
            const float4 ghi = *(const float4*)&lds[tokens[b * LMAX + hi] * DIM + 4 * j];
            const float wl = 1.0f - w;
            val.x = glo.x * wl + ghi.x * w; val.y = glo.y * wl + ghi.y * w;
            val.z = glo.z * wl + ghi.z * w; val.w = glo.w * wl + ghi.w * w;
        }
        out[e] = val;
    }
}

extern "C" void kernel_launch(void* const* d_in, const int* in_sizes, int n_in,
                              void* d_out, int out_size, void* d_ws, size_t ws_size,
                              hipStream_t stream) {
    const float* emb     = (const float*)d_in[0];
    const float* pad     = (const float*)d_in[1];
    const int*   tokens  = (const int*)d_in[2];
    const int*   lengths = (const int*)d_in[3];
    float4* out = (float4*)d_out;

    const size_t desc_bytes = (size_t)NROW * sizeof(int4);  // 5.24 MB
    if (ws_size >= desc_bytes) {
        int4* desc = (int4*)d_ws;
        desc_kernel<<<(NROW + 255) / 256, 256, 0, stream>>>(lengths, tokens, desc);
        emb_kernel<<<NBLK, TPB, 0, stream>>>(emb, pad, desc, out);
    } else {
        emb_kernel_fallback<<<768, 256, 0, stream>>>(emb, pad, tokens, lengths, out);
    }
}